// Round 4
// baseline (841.399 us; speedup 1.0000x reference)
//
#include <hip/hip_runtime.h>
#include <hip/hip_bf16.h>

#define N_NODES   50000
#define N_EDGES   800000
#define D         256
#define N_LAYERS  3
#define N_GRAPHS  64
#define LN_EPS    1e-5f
#define NB_SCAN   ((N_NODES + 255) / 256)   // 196

typedef __attribute__((ext_vector_type(8))) short bf16x8;
typedef __attribute__((ext_vector_type(4))) float f32x4;

__device__ __forceinline__ unsigned short f2bf(float f) {
    unsigned int u = __float_as_uint(f);
    unsigned int r = (u + 0x7FFFu + ((u >> 16) & 1u)) >> 16;
    return (unsigned short)r;
}
__device__ __forceinline__ float bf2f(unsigned short h) {
    return __uint_as_float(((unsigned int)h) << 16);
}

// ---------------------------------------------------------------------------
// x (fp32) -> bf16 scaled by dinv[row]  (hs0 = dinv * x)
__global__ void k_xtobf_s(const float* __restrict__ x, const float* __restrict__ dinv,
                          unsigned short* __restrict__ xb) {
    int gid = blockIdx.x * blockDim.x + threadIdx.x;      // one per 8 elems
    int base = gid * 8;
    if (base >= N_NODES * D) return;
    float sc = dinv[base >> 8];
    const float4* x4 = (const float4*)(x + base);
    float4 a = x4[0], b = x4[1];
    ushort4 lo, hi;
    lo.x = f2bf(a.x * sc); lo.y = f2bf(a.y * sc); lo.z = f2bf(a.z * sc); lo.w = f2bf(a.w * sc);
    hi.x = f2bf(b.x * sc); hi.y = f2bf(b.y * sc); hi.z = f2bf(b.z * sc); hi.w = f2bf(b.w * sc);
    ((ushort4*)(xb + base))[0] = lo;
    ((ushort4*)(xb + base))[1] = hi;
}

// W [l][k][n] fp32 -> Wbt [l][n][k] bf16 (transposed for MFMA loads)
__global__ void k_wtrans(const float* __restrict__ W, unsigned short* __restrict__ Wbt) {
    int gid = blockIdx.x * blockDim.x + threadIdx.x;
    if (gid >= N_LAYERS * D * D) return;
    int l = gid >> 16;
    int rem = gid & 65535;
    int n = rem >> 8;
    int k = rem & 255;
    Wbt[(size_t)l * D * D + n * D + k] = f2bf(W[(size_t)l * D * D + k * D + n]);
}

// ---------------------------------------------------------------------------
__global__ void k_indeg(const int* __restrict__ dst, int* __restrict__ indeg) {
    int e = blockIdx.x * blockDim.x + threadIdx.x;
    if (e < N_EDGES) atomicAdd(&indeg[dst[e]], 1);
}

__global__ void k_dinv(const int* __restrict__ indeg, float* __restrict__ dinv) {
    int n = blockIdx.x * blockDim.x + threadIdx.x;
    if (n < N_NODES) dinv[n] = rsqrtf((float)(indeg[n] + 1));
}

__global__ __launch_bounds__(256) void k_bsum(const int* __restrict__ indeg, int* __restrict__ bsum) {
    int b = blockIdx.x, t = threadIdx.x;
    int i = b * 256 + t;
    int v = (i < N_NODES) ? indeg[i] : 0;
#pragma unroll
    for (int m = 32; m >= 1; m >>= 1) v += __shfl_xor(v, m);
    __shared__ int s[4];
    if ((t & 63) == 0) s[t >> 6] = v;
    __syncthreads();
    if (t == 0) bsum[b] = s[0] + s[1] + s[2] + s[3];
}

__global__ __launch_bounds__(256) void k_bscan(const int* __restrict__ bsum, int* __restrict__ bbase) {
    __shared__ int s[256];
    int t = threadIdx.x;
    int v = (t < NB_SCAN) ? bsum[t] : 0;
    s[t] = v;
    __syncthreads();
    for (int off = 1; off < 256; off <<= 1) {
        int tv = (t >= off) ? s[t - off] : 0;
        __syncthreads();
        s[t] += tv;
        __syncthreads();
    }
    if (t < NB_SCAN) bbase[t] = s[t] - v;
}

__global__ __launch_bounds__(256) void k_offsets(const int* __restrict__ indeg, const int* __restrict__ bbase,
                                                 int* __restrict__ offsets, int* __restrict__ cursor) {
    __shared__ int s[256];
    int b = blockIdx.x, t = threadIdx.x;
    int i = b * 256 + t;
    int v = (i < N_NODES) ? indeg[i] : 0;
    s[t] = v;
    __syncthreads();
    for (int off = 1; off < 256; off <<= 1) {
        int tv = (t >= off) ? s[t - off] : 0;
        __syncthreads();
        s[t] += tv;
        __syncthreads();
    }
    if (i < N_NODES) {
        int o = bbase[b] + s[t] - v;
        offsets[i] = o;
        cursor[i]  = o;
    }
}

// CSR fill: store only src index as uint16 (N_NODES < 65536)
__global__ void k_csr_fill(const int* __restrict__ src, const int* __restrict__ dst,
                           int* __restrict__ cursor, unsigned short* __restrict__ esrc) {
    int e = blockIdx.x * blockDim.x + threadIdx.x;
    if (e >= N_EDGES) return;
    int s = src[e], d = dst[e];
    int pos = atomicAdd(&cursor[d], 1);
    esrc[pos] = (unsigned short)s;
}

__global__ void k_counts_bs(const int* __restrict__ batch, int* __restrict__ counts) {
    int g = threadIdx.x;
    if (g >= N_GRAPHS) return;
    int lo = 0, hi = N_NODES;
    while (lo < hi) { int mid = (lo + hi) >> 1; if (batch[mid] < g) lo = mid + 1; else hi = mid; }
    int start = lo;
    lo = 0; hi = N_NODES;
    int g1 = g + 1;
    while (lo < hi) { int mid = (lo + hi) >> 1; if (batch[mid] < g1) lo = mid + 1; else hi = mid; }
    counts[g] = lo - start;
}

// ---------------------------------------------------------------------------
// dim-partitioned aggregate: agg[n] = dinv[n] * (hs[n] + sum_edges hs[src])
// block part = blockIdx & 7 -> lands on one XCD (round-robin mapping);
// each XCD touches only a 64 B slice of every row -> 3.2 MB, L2-resident.
// wave per (node, part): 16 edge-groups x 4 lanes x 16 B.
__global__ __launch_bounds__(256) void k_agg(const unsigned short* __restrict__ h,
                                             const int* __restrict__ offsets,
                                             const int* __restrict__ indeg,
                                             const float* __restrict__ dinv,
                                             const unsigned short* __restrict__ esrc,
                                             unsigned short* __restrict__ outA) {
    const int part = blockIdx.x & 7;
    const int node = (blockIdx.x >> 3) * 4 + (threadIdx.x >> 6);
    if (node >= N_NODES) return;
    const int lane = threadIdx.x & 63;
    const int eg = lane >> 2;           // edge group 0..15
    const int dl = lane & 3;            // dim sub-slice: 8 dims
    const unsigned short* hp = h + part * 32 + dl * 8;

    float acc[8];
    if (eg == 0) {
        bf16x8 v = *(const bf16x8*)(hp + (size_t)node * 256);
#pragma unroll
        for (int j = 0; j < 8; ++j) acc[j] = bf2f((unsigned short)v[j]);
    } else {
#pragma unroll
        for (int j = 0; j < 8; ++j) acc[j] = 0.f;
    }

    const int beg = offsets[node];
    const int end = beg + indeg[node];
    for (int i = beg + eg; i < end; i += 16) {
        int s = esrc[i];
        bf16x8 v = *(const bf16x8*)(hp + (size_t)s * 256);
#pragma unroll
        for (int j = 0; j < 8; ++j) acc[j] += bf2f((unsigned short)v[j]);
    }

    // reduce over the 16 edge-groups (lanes with equal dl)
#pragma unroll
    for (int m = 4; m <= 32; m <<= 1)
#pragma unroll
        for (int j = 0; j < 8; ++j) acc[j] += __shfl_xor(acc[j], m);

    if (eg == 0) {
        float sc = dinv[node];
        bf16x8 o;
#pragma unroll
        for (int j = 0; j < 8; ++j) o[j] = (short)f2bf(acc[j] * sc);
        *(bf16x8*)(outA + (size_t)node * 256 + part * 32 + dl * 8) = o;
    }
}

// ---------------------------------------------------------------------------
// fused GEMM + bias + LayerNorm + ReLU (+ optional rowscale for next layer's agg)
// C[M,256] = A[M,256] @ Wbt^T ; block = 128 rows, 4 waves x 32 rows
// mfma(Wfrag, xfrag): reg-axis = out-dim, lane&15 = node-row
__global__ __launch_bounds__(256) void k_gemm_ln(const unsigned short* __restrict__ A,
                                                 const unsigned short* __restrict__ Wbt,
                                                 const float* __restrict__ bias,
                                                 const float* __restrict__ gamma,
                                                 const float* __restrict__ beta,
                                                 const float* __restrict__ rowscale,
                                                 unsigned short* __restrict__ out) {
    const int t = threadIdx.x;
    const int lane = t & 63;
    const int w = t >> 6;
    const int lrow = lane & 15;
    const int q = lane >> 4;          // 0..3
    const int mbase = blockIdx.x * 128 + w * 32;

    f32x4 acc[2][16];
#pragma unroll
    for (int mt = 0; mt < 2; ++mt)
#pragma unroll
        for (int nt = 0; nt < 16; ++nt) acc[mt][nt] = (f32x4){0.f, 0.f, 0.f, 0.f};

    int rowA[2];
#pragma unroll
    for (int mt = 0; mt < 2; ++mt) {
        int r = mbase + mt * 16 + lrow;
        rowA[mt] = (r < N_NODES) ? r : (N_NODES - 1);
    }
    const unsigned short* a0 = A + (size_t)rowA[0] * 256 + q * 8;
    const unsigned short* a1 = A + (size_t)rowA[1] * 256 + q * 8;
    const unsigned short* wp = Wbt + (size_t)lrow * 256 + q * 8;

#pragma unroll
    for (int ks = 0; ks < 8; ++ks) {
        bf16x8 av0 = *(const bf16x8*)(a0 + ks * 32);
        bf16x8 av1 = *(const bf16x8*)(a1 + ks * 32);
#pragma unroll
        for (int nt = 0; nt < 16; ++nt) {
            bf16x8 b = *(const bf16x8*)(wp + (size_t)nt * 16 * 256 + ks * 32);
            acc[0][nt] = __builtin_amdgcn_mfma_f32_16x16x32_bf16(b, av0, acc[0][nt], 0, 0, 0);
            acc[1][nt] = __builtin_amdgcn_mfma_f32_16x16x32_bf16(b, av1, acc[1][nt], 0, 0, 0);
        }
    }

    const float4* bias4 = (const float4*)bias;
    const float4* g4 = (const float4*)gamma;
    const float4* be4 = (const float4*)beta;

#pragma unroll
    for (int mt = 0; mt < 2; ++mt) {
        float s = 0.f, s2 = 0.f;
#pragma unroll
        for (int nt = 0; nt < 16; ++nt) {
            float4 bv = bias4[nt * 4 + q];
#pragma unroll
            for (int r = 0; r < 4; ++r) {
                float v = acc[mt][nt][r] + ((const float*)&bv)[r];
                acc[mt][nt][r] = v;
                s += v;
                s2 += v * v;
            }
        }
        s  += __shfl_xor(s, 16);  s  += __shfl_xor(s, 32);
        s2 += __shfl_xor(s2, 16); s2 += __shfl_xor(s2, 32);
        float mu = s * (1.0f / 256.0f);
        float var = s2 * (1.0f / 256.0f) - mu * mu;
        float rs = rsqrtf(var + LN_EPS);

        int row = mbase + mt * 16 + lrow;
        if (row < N_NODES) {
            float sc = (rowscale != nullptr) ? rowscale[row] : 1.0f;
#pragma unroll
            for (int nt = 0; nt < 16; ++nt) {
                float4 gv = g4[nt * 4 + q];
                float4 bev = be4[nt * 4 + q];
                ushort4 o;
                float v0 = fmaxf((acc[mt][nt][0] - mu) * rs * gv.x + bev.x, 0.f) * sc;
                float v1 = fmaxf((acc[mt][nt][1] - mu) * rs * gv.y + bev.y, 0.f) * sc;
                float v2 = fmaxf((acc[mt][nt][2] - mu) * rs * gv.z + bev.z, 0.f) * sc;
                float v3 = fmaxf((acc[mt][nt][3] - mu) * rs * gv.w + bev.w, 0.f) * sc;
                o.x = f2bf(v0); o.y = f2bf(v1); o.z = f2bf(v2); o.w = f2bf(v3);
                *(ushort4*)(out + (size_t)row * 256 + nt * 16 + q * 4) = o;
            }
        }
    }
}

// ---------------------------------------------------------------------------
__global__ __launch_bounds__(256) void k_pool(const unsigned short* __restrict__ h,
                                              const int* __restrict__ batch,
                                              float* __restrict__ sums) {
    __shared__ int sb[128];
    int t = threadIdx.x;
    int n0 = blockIdx.x * 128;
    int cnt = N_NODES - n0; if (cnt > 128) cnt = 128;
    if (cnt <= 0) return;
    if (t < cnt) sb[t] = batch[n0 + t];
    __syncthreads();

    float acc = 0.f;
    int g = sb[0];
    for (int i = 0; i < cnt; ++i) {
        int bg = sb[i];
        if (bg != g) {
            atomicAdd(&sums[g * 256 + t], acc);
            acc = 0.f;
            g = bg;
        }
        acc += bf2f(h[(size_t)(n0 + i) * 256 + t]);
    }
    atomicAdd(&sums[g * 256 + t], acc);
}

__global__ void k_finalize(const float* __restrict__ sums, const int* __restrict__ counts,
                           float* __restrict__ out) {
    int idx = blockIdx.x * blockDim.x + threadIdx.x;
    if (idx < N_GRAPHS * 256) {
        float c = (float)counts[idx >> 8];
        out[idx] = sums[idx] / fmaxf(c, 1.f);
    }
}

// ---------------------------------------------------------------------------
extern "C" void kernel_launch(void* const* d_in, const int* in_sizes, int n_in,
                              void* d_out, int out_size, void* d_ws, size_t ws_size,
                              hipStream_t stream) {
    const float* x     = (const float*)d_in[0];
    const int*   ei    = (const int*)d_in[1];
    const int*   batch = (const int*)d_in[2];
    const float* Ws    = (const float*)d_in[3];
    const float* bs    = (const float*)d_in[4];
    const float* gammas= (const float*)d_in[5];
    const float* betas = (const float*)d_in[6];
    float* out = (float*)d_out;

    const int* src = ei;
    const int* dst = ei + N_EDGES;

    char* p = (char*)d_ws;
    unsigned short* hbf   = (unsigned short*)p; p += (size_t)N_NODES * D * 2;   // 25.6 MB
    unsigned short* aggx  = (unsigned short*)p; p += (size_t)N_NODES * D * 2;   // 25.6 MB
    unsigned short* Wbt   = (unsigned short*)p; p += (size_t)N_LAYERS * D * D * 2;
    int*   indeg  = (int*)p;   p += (size_t)N_NODES * 4;
    int*   offs   = (int*)p;   p += (size_t)N_NODES * 4;
    int*   cursor = (int*)p;   p += (size_t)N_NODES * 4;
    float* dinv   = (float*)p; p += (size_t)N_NODES * 4;
    int*   bsum   = (int*)p;   p += (size_t)NB_SCAN * 4;
    int*   bbase  = (int*)p;   p += (size_t)NB_SCAN * 4;
    unsigned short* esrc = (unsigned short*)p; p += (size_t)N_EDGES * 2;
    float* sums   = (float*)p; p += (size_t)N_GRAPHS * D * 4;
    int*   counts = (int*)p;   p += (size_t)N_GRAPHS * 4;

    hipMemsetAsync(indeg, 0, (size_t)N_NODES * 4, stream);
    hipMemsetAsync(sums, 0, (size_t)N_GRAPHS * D * 4, stream);

    // graph preprocessing (dinv needed before scaled input conversion)
    k_indeg <<<(N_EDGES + 255) / 256, 256, 0, stream>>>(dst, indeg);
    k_dinv  <<<NB_SCAN, 256, 0, stream>>>(indeg, dinv);
    k_xtobf_s<<<(N_NODES * D / 8 + 255) / 256, 256, 0, stream>>>(x, dinv, hbf);
    k_wtrans<<<(N_LAYERS * D * D + 255) / 256, 256, 0, stream>>>(Ws, Wbt);
    k_bsum  <<<NB_SCAN, 256, 0, stream>>>(indeg, bsum);
    k_bscan <<<1, 256, 0, stream>>>(bsum, bbase);
    k_offsets<<<NB_SCAN, 256, 0, stream>>>(indeg, bbase, offs, cursor);
    k_csr_fill<<<(N_EDGES + 255) / 256, 256, 0, stream>>>(src, dst, cursor, esrc);
    k_counts_bs<<<1, 64, 0, stream>>>(batch, counts);

    // 3 GCN layers: aggregate-first; hs = dinv*h carried between layers
    const int agg_grid  = ((N_NODES + 3) / 4) * 8;
    const int gemm_grid = (N_NODES + 127) / 128;
    for (int l = 0; l < N_LAYERS; ++l) {
        k_agg<<<agg_grid, 256, 0, stream>>>(hbf, offs, indeg, dinv, esrc, aggx);
        const float* rsc = (l == N_LAYERS - 1) ? nullptr : dinv;
        k_gemm_ln<<<gemm_grid, 256, 0, stream>>>(aggx, Wbt + (size_t)l * D * D,
                                                 bs + (size_t)l * D,
                                                 gammas + (size_t)l * D,
                                                 betas + (size_t)l * D, rsc, hbf);
    }

    // global mean pool (last layer wrote unscaled h)
    k_pool<<<(N_NODES + 127) / 128, 256, 0, stream>>>(hbf, batch, sums);
    k_finalize<<<(N_GRAPHS * 256 + 255) / 256, 256, 0, stream>>>(sums, counts, out);
}

// Round 5
// 532.291 us; speedup vs baseline: 1.5807x; 1.5807x over previous
//
#include <hip/hip_runtime.h>
#include <hip/hip_bf16.h>

#define N_NODES   50000
#define N_EDGES   800000
#define D         256
#define N_LAYERS  3
#define N_GRAPHS  64
#define LN_EPS    1e-5f
#define NB_SCAN   ((N_NODES + 255) / 256)   // 196

typedef __attribute__((ext_vector_type(8))) short bf16x8;
typedef __attribute__((ext_vector_type(4))) float f32x4;

__device__ __forceinline__ unsigned short f2bf(float f) {
    unsigned int u = __float_as_uint(f);
    unsigned int r = (u + 0x7FFFu + ((u >> 16) & 1u)) >> 16;
    return (unsigned short)r;
}
__device__ __forceinline__ float bf2f(unsigned short h) {
    return __uint_as_float(((unsigned int)h) << 16);
}

// ---------------------------------------------------------------------------
// x (fp32) -> bf16 scaled by dinv[row]  (hs0 = dinv * x)
__global__ void k_xtobf_s(const float* __restrict__ x, const float* __restrict__ dinv,
                          unsigned short* __restrict__ xb) {
    int gid = blockIdx.x * blockDim.x + threadIdx.x;      // one per 8 elems
    int base = gid * 8;
    if (base >= N_NODES * D) return;
    float sc = dinv[base >> 8];
    const float4* x4 = (const float4*)(x + base);
    float4 a = x4[0], b = x4[1];
    ushort4 lo, hi;
    lo.x = f2bf(a.x * sc); lo.y = f2bf(a.y * sc); lo.z = f2bf(a.z * sc); lo.w = f2bf(a.w * sc);
    hi.x = f2bf(b.x * sc); hi.y = f2bf(b.y * sc); hi.z = f2bf(b.z * sc); hi.w = f2bf(b.w * sc);
    ((ushort4*)(xb + base))[0] = lo;
    ((ushort4*)(xb + base))[1] = hi;
}

// W [l][k][n] fp32 -> Wbt [l][n][k] bf16 (transposed for MFMA loads)
__global__ void k_wtrans(const float* __restrict__ W, unsigned short* __restrict__ Wbt) {
    int gid = blockIdx.x * blockDim.x + threadIdx.x;
    if (gid >= N_LAYERS * D * D) return;
    int l = gid >> 16;
    int rem = gid & 65535;
    int n = rem >> 8;
    int k = rem & 255;
    Wbt[(size_t)l * D * D + n * D + k] = f2bf(W[(size_t)l * D * D + k * D + n]);
}

// ---------------------------------------------------------------------------
__global__ void k_indeg(const int* __restrict__ dst, int* __restrict__ indeg) {
    int e = blockIdx.x * blockDim.x + threadIdx.x;
    if (e < N_EDGES) atomicAdd(&indeg[dst[e]], 1);
}

__global__ void k_dinv(const int* __restrict__ indeg, float* __restrict__ dinv) {
    int n = blockIdx.x * blockDim.x + threadIdx.x;
    if (n < N_NODES) dinv[n] = rsqrtf((float)(indeg[n] + 1));
}

__global__ __launch_bounds__(256) void k_bsum(const int* __restrict__ indeg, int* __restrict__ bsum) {
    int b = blockIdx.x, t = threadIdx.x;
    int i = b * 256 + t;
    int v = (i < N_NODES) ? indeg[i] : 0;
#pragma unroll
    for (int m = 32; m >= 1; m >>= 1) v += __shfl_xor(v, m);
    __shared__ int s[4];
    if ((t & 63) == 0) s[t >> 6] = v;
    __syncthreads();
    if (t == 0) bsum[b] = s[0] + s[1] + s[2] + s[3];
}

__global__ __launch_bounds__(256) void k_bscan(const int* __restrict__ bsum, int* __restrict__ bbase) {
    __shared__ int s[256];
    int t = threadIdx.x;
    int v = (t < NB_SCAN) ? bsum[t] : 0;
    s[t] = v;
    __syncthreads();
    for (int off = 1; off < 256; off <<= 1) {
        int tv = (t >= off) ? s[t - off] : 0;
        __syncthreads();
        s[t] += tv;
        __syncthreads();
    }
    if (t < NB_SCAN) bbase[t] = s[t] - v;
}

__global__ __launch_bounds__(256) void k_offsets(const int* __restrict__ indeg, const int* __restrict__ bbase,
                                                 int* __restrict__ offsets, int* __restrict__ cursor) {
    __shared__ int s[256];
    int b = blockIdx.x, t = threadIdx.x;
    int i = b * 256 + t;
    int v = (i < N_NODES) ? indeg[i] : 0;
    s[t] = v;
    __syncthreads();
    for (int off = 1; off < 256; off <<= 1) {
        int tv = (t >= off) ? s[t - off] : 0;
        __syncthreads();
        s[t] += tv;
        __syncthreads();
    }
    if (i < N_NODES) {
        int o = bbase[b] + s[t] - v;
        offsets[i] = o;
        cursor[i]  = o;
    }
}

// CSR fill: store only src index as uint16 (N_NODES < 65536)
__global__ void k_csr_fill(const int* __restrict__ src, const int* __restrict__ dst,
                           int* __restrict__ cursor, unsigned short* __restrict__ esrc) {
    int e = blockIdx.x * blockDim.x + threadIdx.x;
    if (e >= N_EDGES) return;
    int s = src[e], d = dst[e];
    int pos = atomicAdd(&cursor[d], 1);
    esrc[pos] = (unsigned short)s;
}

__global__ void k_counts_bs(const int* __restrict__ batch, int* __restrict__ counts) {
    int g = threadIdx.x;
    if (g >= N_GRAPHS) return;
    int lo = 0, hi = N_NODES;
    while (lo < hi) { int mid = (lo + hi) >> 1; if (batch[mid] < g) lo = mid + 1; else hi = mid; }
    int start = lo;
    lo = 0; hi = N_NODES;
    int g1 = g + 1;
    while (lo < hi) { int mid = (lo + hi) >> 1; if (batch[mid] < g1) lo = mid + 1; else hi = mid; }
    counts[g] = lo - start;
}

// ---------------------------------------------------------------------------
// aggregate: agg[n] = dinv[n] * (hs[n] + sum_edges hs[src])
// one wave per node; half-wave (32 lanes x 16 B) covers a full 512 B row;
// 4 edges per half-wave iteration -> 8 rows in flight per wave.
__global__ __launch_bounds__(256) void k_agg(const unsigned short* __restrict__ h,
                                             const int* __restrict__ offsets,
                                             const int* __restrict__ indeg,
                                             const float* __restrict__ dinv,
                                             const unsigned short* __restrict__ esrc,
                                             unsigned short* __restrict__ outA) {
    const int node = blockIdx.x * 4 + (threadIdx.x >> 6);
    const int lane = threadIdx.x & 63;
    if (node >= N_NODES) return;
    const int hw = lane >> 5;       // which edge of the interleaved pair
    const int dl = lane & 31;       // dim-lane: dims dl*8 .. dl*8+7
    const unsigned short* hp = h + dl * 8;

    float acc[8];
    if (hw == 0) {
        bf16x8 v = *(const bf16x8*)(hp + (size_t)node * 256);
#pragma unroll
        for (int j = 0; j < 8; ++j) acc[j] = bf2f((unsigned short)v[j]);
    } else {
#pragma unroll
        for (int j = 0; j < 8; ++j) acc[j] = 0.f;
    }

    const int beg = offsets[node];
    const int end = beg + indeg[node];
    int i = beg + hw;
    // 4-unroll per half-wave: edges i, i+2, i+4, i+6 (8 rows in flight per wave)
    for (; i + 6 < end; i += 8) {
        int s0 = esrc[i];
        int s1 = esrc[i + 2];
        int s2 = esrc[i + 4];
        int s3 = esrc[i + 6];
        bf16x8 v0 = *(const bf16x8*)(hp + (size_t)s0 * 256);
        bf16x8 v1 = *(const bf16x8*)(hp + (size_t)s1 * 256);
        bf16x8 v2 = *(const bf16x8*)(hp + (size_t)s2 * 256);
        bf16x8 v3 = *(const bf16x8*)(hp + (size_t)s3 * 256);
#pragma unroll
        for (int j = 0; j < 8; ++j) acc[j] += bf2f((unsigned short)v0[j]);
#pragma unroll
        for (int j = 0; j < 8; ++j) acc[j] += bf2f((unsigned short)v1[j]);
#pragma unroll
        for (int j = 0; j < 8; ++j) acc[j] += bf2f((unsigned short)v2[j]);
#pragma unroll
        for (int j = 0; j < 8; ++j) acc[j] += bf2f((unsigned short)v3[j]);
    }
    for (; i < end; i += 2) {
        int s0 = esrc[i];
        bf16x8 v0 = *(const bf16x8*)(hp + (size_t)s0 * 256);
#pragma unroll
        for (int j = 0; j < 8; ++j) acc[j] += bf2f((unsigned short)v0[j]);
    }

    // combine the two half-waves
#pragma unroll
    for (int j = 0; j < 8; ++j) acc[j] += __shfl_xor(acc[j], 32);

    if (hw == 0) {
        float sc = dinv[node];
        bf16x8 o;
#pragma unroll
        for (int j = 0; j < 8; ++j) o[j] = (short)f2bf(acc[j] * sc);
        *(bf16x8*)(outA + (size_t)node * 256 + dl * 8) = o;
    }
}

// ---------------------------------------------------------------------------
// fused GEMM + bias + LayerNorm + ReLU (+ optional rowscale for next layer's agg)
// C[M,256] = A[M,256] @ Wbt^T ; block = 128 rows, 4 waves x 32 rows
// mfma(Wfrag, xfrag): reg-axis = out-dim, lane&15 = node-row
__global__ __launch_bounds__(256) void k_gemm_ln(const unsigned short* __restrict__ A,
                                                 const unsigned short* __restrict__ Wbt,
                                                 const float* __restrict__ bias,
                                                 const float* __restrict__ gamma,
                                                 const float* __restrict__ beta,
                                                 const float* __restrict__ rowscale,
                                                 unsigned short* __restrict__ out) {
    const int t = threadIdx.x;
    const int lane = t & 63;
    const int w = t >> 6;
    const int lrow = lane & 15;
    const int q = lane >> 4;          // 0..3
    const int mbase = blockIdx.x * 128 + w * 32;

    f32x4 acc[2][16];
#pragma unroll
    for (int mt = 0; mt < 2; ++mt)
#pragma unroll
        for (int nt = 0; nt < 16; ++nt) acc[mt][nt] = (f32x4){0.f, 0.f, 0.f, 0.f};

    int rowA[2];
#pragma unroll
    for (int mt = 0; mt < 2; ++mt) {
        int r = mbase + mt * 16 + lrow;
        rowA[mt] = (r < N_NODES) ? r : (N_NODES - 1);
    }
    const unsigned short* a0 = A + (size_t)rowA[0] * 256 + q * 8;
    const unsigned short* a1 = A + (size_t)rowA[1] * 256 + q * 8;
    const unsigned short* wp = Wbt + (size_t)lrow * 256 + q * 8;

#pragma unroll
    for (int ks = 0; ks < 8; ++ks) {
        bf16x8 av0 = *(const bf16x8*)(a0 + ks * 32);
        bf16x8 av1 = *(const bf16x8*)(a1 + ks * 32);
#pragma unroll
        for (int nt = 0; nt < 16; ++nt) {
            bf16x8 b = *(const bf16x8*)(wp + (size_t)nt * 16 * 256 + ks * 32);
            acc[0][nt] = __builtin_amdgcn_mfma_f32_16x16x32_bf16(b, av0, acc[0][nt], 0, 0, 0);
            acc[1][nt] = __builtin_amdgcn_mfma_f32_16x16x32_bf16(b, av1, acc[1][nt], 0, 0, 0);
        }
    }

    const float4* bias4 = (const float4*)bias;
    const float4* g4 = (const float4*)gamma;
    const float4* be4 = (const float4*)beta;

#pragma unroll
    for (int mt = 0; mt < 2; ++mt) {
        float s = 0.f, s2 = 0.f;
#pragma unroll
        for (int nt = 0; nt < 16; ++nt) {
            float4 bv = bias4[nt * 4 + q];
#pragma unroll
            for (int r = 0; r < 4; ++r) {
                float v = acc[mt][nt][r] + ((const float*)&bv)[r];
                acc[mt][nt][r] = v;
                s += v;
                s2 += v * v;
            }
        }
        s  += __shfl_xor(s, 16);  s  += __shfl_xor(s, 32);
        s2 += __shfl_xor(s2, 16); s2 += __shfl_xor(s2, 32);
        float mu = s * (1.0f / 256.0f);
        float var = s2 * (1.0f / 256.0f) - mu * mu;
        float rs = rsqrtf(var + LN_EPS);

        int row = mbase + mt * 16 + lrow;
        if (row < N_NODES) {
            float sc = (rowscale != nullptr) ? rowscale[row] : 1.0f;
#pragma unroll
            for (int nt = 0; nt < 16; ++nt) {
                float4 gv = g4[nt * 4 + q];
                float4 bev = be4[nt * 4 + q];
                ushort4 o;
                float v0 = fmaxf((acc[mt][nt][0] - mu) * rs * gv.x + bev.x, 0.f) * sc;
                float v1 = fmaxf((acc[mt][nt][1] - mu) * rs * gv.y + bev.y, 0.f) * sc;
                float v2 = fmaxf((acc[mt][nt][2] - mu) * rs * gv.z + bev.z, 0.f) * sc;
                float v3 = fmaxf((acc[mt][nt][3] - mu) * rs * gv.w + bev.w, 0.f) * sc;
                o.x = f2bf(v0); o.y = f2bf(v1); o.z = f2bf(v2); o.w = f2bf(v3);
                *(ushort4*)(out + (size_t)row * 256 + nt * 16 + q * 4) = o;
            }
        }
    }
}

// ---------------------------------------------------------------------------
__global__ __launch_bounds__(256) void k_pool(const unsigned short* __restrict__ h,
                                              const int* __restrict__ batch,
                                              float* __restrict__ sums) {
    __shared__ int sb[128];
    int t = threadIdx.x;
    int n0 = blockIdx.x * 128;
    int cnt = N_NODES - n0; if (cnt > 128) cnt = 128;
    if (cnt <= 0) return;
    if (t < cnt) sb[t] = batch[n0 + t];
    __syncthreads();

    float acc = 0.f;
    int g = sb[0];
    for (int i = 0; i < cnt; ++i) {
        int bg = sb[i];
        if (bg != g) {
            atomicAdd(&sums[g * 256 + t], acc);
            acc = 0.f;
            g = bg;
        }
        acc += bf2f(h[(size_t)(n0 + i) * 256 + t]);
    }
    atomicAdd(&sums[g * 256 + t], acc);
}

__global__ void k_finalize(const float* __restrict__ sums, const int* __restrict__ counts,
                           float* __restrict__ out) {
    int idx = blockIdx.x * blockDim.x + threadIdx.x;
    if (idx < N_GRAPHS * 256) {
        float c = (float)counts[idx >> 8];
        out[idx] = sums[idx] / fmaxf(c, 1.f);
    }
}

// ---------------------------------------------------------------------------
extern "C" void kernel_launch(void* const* d_in, const int* in_sizes, int n_in,
                              void* d_out, int out_size, void* d_ws, size_t ws_size,
                              hipStream_t stream) {
    const float* x     = (const float*)d_in[0];
    const int*   ei    = (const int*)d_in[1];
    const int*   batch = (const int*)d_in[2];
    const float* Ws    = (const float*)d_in[3];
    const float* bs    = (const float*)d_in[4];
    const float* gammas= (const float*)d_in[5];
    const float* betas = (const float*)d_in[6];
    float* out = (float*)d_out;

    const int* src = ei;
    const int* dst = ei + N_EDGES;

    char* p = (char*)d_ws;
    unsigned short* hbf   = (unsigned short*)p; p += (size_t)N_NODES * D * 2;   // 25.6 MB
    unsigned short* aggx  = (unsigned short*)p; p += (size_t)N_NODES * D * 2;   // 25.6 MB
    unsigned short* Wbt   = (unsigned short*)p; p += (size_t)N_LAYERS * D * D * 2;
    int*   indeg  = (int*)p;   p += (size_t)N_NODES * 4;
    int*   offs   = (int*)p;   p += (size_t)N_NODES * 4;
    int*   cursor = (int*)p;   p += (size_t)N_NODES * 4;
    float* dinv   = (float*)p; p += (size_t)N_NODES * 4;
    int*   bsum   = (int*)p;   p += (size_t)NB_SCAN * 4;
    int*   bbase  = (int*)p;   p += (size_t)NB_SCAN * 4;
    unsigned short* esrc = (unsigned short*)p; p += (size_t)N_EDGES * 2;
    float* sums   = (float*)p; p += (size_t)N_GRAPHS * D * 4;
    int*   counts = (int*)p;   p += (size_t)N_GRAPHS * 4;

    hipMemsetAsync(indeg, 0, (size_t)N_NODES * 4, stream);
    hipMemsetAsync(sums, 0, (size_t)N_GRAPHS * D * 4, stream);

    // graph preprocessing (dinv needed before scaled input conversion)
    k_indeg <<<(N_EDGES + 255) / 256, 256, 0, stream>>>(dst, indeg);
    k_dinv  <<<NB_SCAN, 256, 0, stream>>>(indeg, dinv);
    k_xtobf_s<<<(N_NODES * D / 8 + 255) / 256, 256, 0, stream>>>(x, dinv, hbf);
    k_wtrans<<<(N_LAYERS * D * D + 255) / 256, 256, 0, stream>>>(Ws, Wbt);
    k_bsum  <<<NB_SCAN, 256, 0, stream>>>(indeg, bsum);
    k_bscan <<<1, 256, 0, stream>>>(bsum, bbase);
    k_offsets<<<NB_SCAN, 256, 0, stream>>>(indeg, bbase, offs, cursor);
    k_csr_fill<<<(N_EDGES + 255) / 256, 256, 0, stream>>>(src, dst, cursor, esrc);
    k_counts_bs<<<1, 64, 0, stream>>>(batch, counts);

    // 3 GCN layers: aggregate-first; hs = dinv*h carried between layers
    const int agg_grid  = (N_NODES + 3) / 4;
    const int gemm_grid = (N_NODES + 127) / 128;
    for (int l = 0; l < N_LAYERS; ++l) {
        k_agg<<<agg_grid, 256, 0, stream>>>(hbf, offs, indeg, dinv, esrc, aggx);
        const float* rsc = (l == N_LAYERS - 1) ? nullptr : dinv;
        k_gemm_ln<<<gemm_grid, 256, 0, stream>>>(aggx, Wbt + (size_t)l * D * D,
                                                 bs + (size_t)l * D,
                                                 gammas + (size_t)l * D,
                                                 betas + (size_t)l * D, rsc, hbf);
    }

    // global mean pool (last layer wrote unscaled h)
    k_pool<<<(N_NODES + 127) / 128, 256, 0, stream>>>(hbf, batch, sums);
    k_finalize<<<(N_GRAPHS * 256 + 255) / 256, 256, 0, stream>>>(sums, counts, out);
}

// Round 6
// 465.926 us; speedup vs baseline: 1.8059x; 1.1424x over previous
//
#include <hip/hip_runtime.h>
#include <hip/hip_bf16.h>

#define N_NODES   50000
#define N_EDGES   800000
#define D         256
#define N_LAYERS  3
#define N_GRAPHS  64
#define LN_EPS    1e-5f
#define NB_SCAN   ((N_NODES + 255) / 256)   // 196

typedef __attribute__((ext_vector_type(8))) short bf16x8;
typedef __attribute__((ext_vector_type(4))) float f32x4;

__device__ __forceinline__ unsigned short f2bf(float f) {
    unsigned int u = __float_as_uint(f);
    unsigned int r = (u + 0x7FFFu + ((u >> 16) & 1u)) >> 16;
    return (unsigned short)r;
}
__device__ __forceinline__ float bf2f(unsigned short h) {
    return __uint_as_float(((unsigned int)h) << 16);
}

// ---------------------------------------------------------------------------
// x (fp32) -> bf16 scaled by dinv[row]  (hs0 = dinv * x)
__global__ void k_xtobf_s(const float* __restrict__ x, const float* __restrict__ dinv,
                          unsigned short* __restrict__ xb) {
    int gid = blockIdx.x * blockDim.x + threadIdx.x;      // one per 8 elems
    int base = gid * 8;
    if (base >= N_NODES * D) return;
    float sc = dinv[base >> 8];
    const float4* x4 = (const float4*)(x + base);
    float4 a = x4[0], b = x4[1];
    ushort4 lo, hi;
    lo.x = f2bf(a.x * sc); lo.y = f2bf(a.y * sc); lo.z = f2bf(a.z * sc); lo.w = f2bf(a.w * sc);
    hi.x = f2bf(b.x * sc); hi.y = f2bf(b.y * sc); hi.z = f2bf(b.z * sc); hi.w = f2bf(b.w * sc);
    ((ushort4*)(xb + base))[0] = lo;
    ((ushort4*)(xb + base))[1] = hi;
}

// W [l][k][n] fp32 -> Wbt [l][n][k] bf16 (transposed for MFMA loads)
__global__ void k_wtrans(const float* __restrict__ W, unsigned short* __restrict__ Wbt) {
    int gid = blockIdx.x * blockDim.x + threadIdx.x;
    if (gid >= N_LAYERS * D * D) return;
    int l = gid >> 16;
    int rem = gid & 65535;
    int n = rem >> 8;
    int k = rem & 255;
    Wbt[(size_t)l * D * D + n * D + k] = f2bf(W[(size_t)l * D * D + k * D + n]);
}

// ---------------------------------------------------------------------------
__global__ void k_indeg(const int* __restrict__ dst, int* __restrict__ indeg) {
    int e = blockIdx.x * blockDim.x + threadIdx.x;
    if (e < N_EDGES) atomicAdd(&indeg[dst[e]], 1);
}

__global__ void k_dinv(const int* __restrict__ indeg, float* __restrict__ dinv) {
    int n = blockIdx.x * blockDim.x + threadIdx.x;
    if (n < N_NODES) dinv[n] = rsqrtf((float)(indeg[n] + 1));
}

__global__ __launch_bounds__(256) void k_bsum(const int* __restrict__ indeg, int* __restrict__ bsum) {
    int b = blockIdx.x, t = threadIdx.x;
    int i = b * 256 + t;
    int v = (i < N_NODES) ? indeg[i] : 0;
#pragma unroll
    for (int m = 32; m >= 1; m >>= 1) v += __shfl_xor(v, m);
    __shared__ int s[4];
    if ((t & 63) == 0) s[t >> 6] = v;
    __syncthreads();
    if (t == 0) bsum[b] = s[0] + s[1] + s[2] + s[3];
}

__global__ __launch_bounds__(256) void k_bscan(const int* __restrict__ bsum, int* __restrict__ bbase) {
    __shared__ int s[256];
    int t = threadIdx.x;
    int v = (t < NB_SCAN) ? bsum[t] : 0;
    s[t] = v;
    __syncthreads();
    for (int off = 1; off < 256; off <<= 1) {
        int tv = (t >= off) ? s[t - off] : 0;
        __syncthreads();
        s[t] += tv;
        __syncthreads();
    }
    if (t < NB_SCAN) bbase[t] = s[t] - v;
}

__global__ __launch_bounds__(256) void k_offsets(const int* __restrict__ indeg, const int* __restrict__ bbase,
                                                 int* __restrict__ offsets, int* __restrict__ cursor) {
    __shared__ int s[256];
    int b = blockIdx.x, t = threadIdx.x;
    int i = b * 256 + t;
    int v = (i < N_NODES) ? indeg[i] : 0;
    s[t] = v;
    __syncthreads();
    for (int off = 1; off < 256; off <<= 1) {
        int tv = (t >= off) ? s[t - off] : 0;
        __syncthreads();
        s[t] += tv;
        __syncthreads();
    }
    if (i < N_NODES) {
        int o = bbase[b] + s[t] - v;
        offsets[i] = o;
        cursor[i]  = o;
    }
}

// CSR fill: store only src index as uint16 (N_NODES < 65536)
__global__ void k_csr_fill(const int* __restrict__ src, const int* __restrict__ dst,
                           int* __restrict__ cursor, unsigned short* __restrict__ esrc) {
    int e = blockIdx.x * blockDim.x + threadIdx.x;
    if (e >= N_EDGES) return;
    int s = src[e], d = dst[e];
    int pos = atomicAdd(&cursor[d], 1);
    esrc[pos] = (unsigned short)s;
}

__global__ void k_counts_bs(const int* __restrict__ batch, int* __restrict__ counts) {
    int g = threadIdx.x;
    if (g >= N_GRAPHS) return;
    int lo = 0, hi = N_NODES;
    while (lo < hi) { int mid = (lo + hi) >> 1; if (batch[mid] < g) lo = mid + 1; else hi = mid; }
    int start = lo;
    lo = 0; hi = N_NODES;
    int g1 = g + 1;
    while (lo < hi) { int mid = (lo + hi) >> 1; if (batch[mid] < g1) lo = mid + 1; else hi = mid; }
    counts[g] = lo - start;
}

// ---------------------------------------------------------------------------
// aggregate: agg[n] = dinv[n] * (hs[n] + sum_edges hs[src])
// one wave per node; half-wave (32 lanes x 16 B) covers a full 512 B row;
// 4 edges per half-wave iteration -> 8 rows in flight per wave.
__global__ __launch_bounds__(256) void k_agg(const unsigned short* __restrict__ h,
                                             const int* __restrict__ offsets,
                                             const int* __restrict__ indeg,
                                             const float* __restrict__ dinv,
                                             const unsigned short* __restrict__ esrc,
                                             unsigned short* __restrict__ outA) {
    const int node = blockIdx.x * 4 + (threadIdx.x >> 6);
    const int lane = threadIdx.x & 63;
    if (node >= N_NODES) return;
    const int hw = lane >> 5;       // which edge of the interleaved pair
    const int dl = lane & 31;       // dim-lane: dims dl*8 .. dl*8+7
    const unsigned short* hp = h + dl * 8;

    float acc[8];
    if (hw == 0) {
        bf16x8 v = *(const bf16x8*)(hp + (size_t)node * 256);
#pragma unroll
        for (int j = 0; j < 8; ++j) acc[j] = bf2f((unsigned short)v[j]);
    } else {
#pragma unroll
        for (int j = 0; j < 8; ++j) acc[j] = 0.f;
    }

    const int beg = offsets[node];
    const int end = beg + indeg[node];
    int i = beg + hw;
    // 4-unroll per half-wave: edges i, i+2, i+4, i+6 (8 rows in flight per wave)
    for (; i + 6 < end; i += 8) {
        int s0 = esrc[i];
        int s1 = esrc[i + 2];
        int s2 = esrc[i + 4];
        int s3 = esrc[i + 6];
        bf16x8 v0 = *(const bf16x8*)(hp + (size_t)s0 * 256);
        bf16x8 v1 = *(const bf16x8*)(hp + (size_t)s1 * 256);
        bf16x8 v2 = *(const bf16x8*)(hp + (size_t)s2 * 256);
        bf16x8 v3 = *(const bf16x8*)(hp + (size_t)s3 * 256);
#pragma unroll
        for (int j = 0; j < 8; ++j) acc[j] += bf2f((unsigned short)v0[j]);
#pragma unroll
        for (int j = 0; j < 8; ++j) acc[j] += bf2f((unsigned short)v1[j]);
#pragma unroll
        for (int j = 0; j < 8; ++j) acc[j] += bf2f((unsigned short)v2[j]);
#pragma unroll
        for (int j = 0; j < 8; ++j) acc[j] += bf2f((unsigned short)v3[j]);
    }
    for (; i < end; i += 2) {
        int s0 = esrc[i];
        bf16x8 v0 = *(const bf16x8*)(hp + (size_t)s0 * 256);
#pragma unroll
        for (int j = 0; j < 8; ++j) acc[j] += bf2f((unsigned short)v0[j]);
    }

    // combine the two half-waves
#pragma unroll
    for (int j = 0; j < 8; ++j) acc[j] += __shfl_xor(acc[j], 32);

    if (hw == 0) {
        float sc = dinv[node];
        bf16x8 o;
#pragma unroll
        for (int j = 0; j < 8; ++j) o[j] = (short)f2bf(acc[j] * sc);
        *(bf16x8*)(outA + (size_t)node * 256 + dl * 8) = o;
    }
}

// ---------------------------------------------------------------------------
// fused GEMM + bias + LayerNorm + ReLU (+ optional rowscale for next layer's agg)
// C[M,256] = A[M,256] @ Wbt^T ; block = 128 rows, 4 waves x 32 rows
// W staged in LDS in two 64 KB K-phases, 16 B chunks XOR-swizzled (c ^= n&7)
// mfma(Wfrag, xfrag): reg-axis = out-dim, lane&15 = node-row
__global__ __launch_bounds__(256) void k_gemm_ln(const unsigned short* __restrict__ A,
                                                 const unsigned short* __restrict__ Wbt,
                                                 const float* __restrict__ bias,
                                                 const float* __restrict__ gamma,
                                                 const float* __restrict__ beta,
                                                 const float* __restrict__ rowscale,
                                                 unsigned short* __restrict__ out) {
    __shared__ short wlds[256 * 128];   // 64 KB: rows n=0..255, k-half 128
    const int t = threadIdx.x;
    const int lane = t & 63;
    const int w = t >> 6;
    const int lrow = lane & 15;
    const int q = lane >> 4;          // 0..3
    const int mbase = blockIdx.x * 128 + w * 32;

    f32x4 acc[2][16];
#pragma unroll
    for (int mt = 0; mt < 2; ++mt)
#pragma unroll
        for (int nt = 0; nt < 16; ++nt) acc[mt][nt] = (f32x4){0.f, 0.f, 0.f, 0.f};

    int rowA[2];
#pragma unroll
    for (int mt = 0; mt < 2; ++mt) {
        int r = mbase + mt * 16 + lrow;
        rowA[mt] = (r < N_NODES) ? r : (N_NODES - 1);
    }
    const unsigned short* a0 = A + (size_t)rowA[0] * 256 + q * 8;
    const unsigned short* a1 = A + (size_t)rowA[1] * 256 + q * 8;

#pragma unroll
    for (int ph = 0; ph < 2; ++ph) {
        if (ph) __syncthreads();   // all waves done reading previous half
        // stage W k-half: coalesced global read, swizzled ds_write_b128
#pragma unroll
        for (int it = 0; it < 16; ++it) {
            int L = it * 256 + t;           // 16B-chunk id 0..4095
            int n = L >> 4;                 // W row 0..255
            int c = L & 15;                 // chunk within 256 B row-half
            bf16x8 v = *(const bf16x8*)(Wbt + (size_t)n * 256 + ph * 128 + c * 8);
            int cs = c ^ (n & 7);
            *(bf16x8*)(wlds + n * 128 + cs * 8) = v;
        }
        __syncthreads();

        // A fragments for this k-half (issued up front)
        bf16x8 av0[4], av1[4];
#pragma unroll
        for (int ks = 0; ks < 4; ++ks) {
            av0[ks] = *(const bf16x8*)(a0 + ph * 128 + ks * 32);
            av1[ks] = *(const bf16x8*)(a1 + ph * 128 + ks * 32);
        }

#pragma unroll
        for (int ks = 0; ks < 4; ++ks) {
#pragma unroll
            for (int nt = 0; nt < 16; ++nt) {
                int n = nt * 16 + lrow;
                int cs = (ks * 4 + q) ^ (n & 7);
                bf16x8 b = *(const bf16x8*)(wlds + n * 128 + cs * 8);
                acc[0][nt] = __builtin_amdgcn_mfma_f32_16x16x32_bf16(b, av0[ks], acc[0][nt], 0, 0, 0);
                acc[1][nt] = __builtin_amdgcn_mfma_f32_16x16x32_bf16(b, av1[ks], acc[1][nt], 0, 0, 0);
            }
        }
    }

    const float4* bias4 = (const float4*)bias;
    const float4* g4 = (const float4*)gamma;
    const float4* be4 = (const float4*)beta;

#pragma unroll
    for (int mt = 0; mt < 2; ++mt) {
        float s = 0.f, s2 = 0.f;
#pragma unroll
        for (int nt = 0; nt < 16; ++nt) {
            float4 bv = bias4[nt * 4 + q];
#pragma unroll
            for (int r = 0; r < 4; ++r) {
                float v = acc[mt][nt][r] + ((const float*)&bv)[r];
                acc[mt][nt][r] = v;
                s += v;
                s2 += v * v;
            }
        }
        s  += __shfl_xor(s, 16);  s  += __shfl_xor(s, 32);
        s2 += __shfl_xor(s2, 16); s2 += __shfl_xor(s2, 32);
        float mu = s * (1.0f / 256.0f);
        float var = s2 * (1.0f / 256.0f) - mu * mu;
        float rs = rsqrtf(var + LN_EPS);

        int row = mbase + mt * 16 + lrow;
        if (row < N_NODES) {
            float sc = (rowscale != nullptr) ? rowscale[row] : 1.0f;
#pragma unroll
            for (int nt = 0; nt < 16; ++nt) {
                float4 gv = g4[nt * 4 + q];
                float4 bev = be4[nt * 4 + q];
                ushort4 o;
                float v0 = fmaxf((acc[mt][nt][0] - mu) * rs * gv.x + bev.x, 0.f) * sc;
                float v1 = fmaxf((acc[mt][nt][1] - mu) * rs * gv.y + bev.y, 0.f) * sc;
                float v2 = fmaxf((acc[mt][nt][2] - mu) * rs * gv.z + bev.z, 0.f) * sc;
                float v3 = fmaxf((acc[mt][nt][3] - mu) * rs * gv.w + bev.w, 0.f) * sc;
                o.x = f2bf(v0); o.y = f2bf(v1); o.z = f2bf(v2); o.w = f2bf(v3);
                *(ushort4*)(out + (size_t)row * 256 + nt * 16 + q * 4) = o;
            }
        }
    }
}

// ---------------------------------------------------------------------------
__global__ __launch_bounds__(256) void k_pool(const unsigned short* __restrict__ h,
                                              const int* __restrict__ batch,
                                              float* __restrict__ sums) {
    __shared__ int sb[128];
    int t = threadIdx.x;
    int n0 = blockIdx.x * 128;
    int cnt = N_NODES - n0; if (cnt > 128) cnt = 128;
    if (cnt <= 0) return;
    if (t < cnt) sb[t] = batch[n0 + t];
    __syncthreads();

    float acc = 0.f;
    int g = sb[0];
    for (int i = 0; i < cnt; ++i) {
        int bg = sb[i];
        if (bg != g) {
            atomicAdd(&sums[g * 256 + t], acc);
            acc = 0.f;
            g = bg;
        }
        acc += bf2f(h[(size_t)(n0 + i) * 256 + t]);
    }
    atomicAdd(&sums[g * 256 + t], acc);
}

__global__ void k_finalize(const float* __restrict__ sums, const int* __restrict__ counts,
                           float* __restrict__ out) {
    int idx = blockIdx.x * blockDim.x + threadIdx.x;
    if (idx < N_GRAPHS * 256) {
        float c = (float)counts[idx >> 8];
        out[idx] = sums[idx] / fmaxf(c, 1.f);
    }
}

// ---------------------------------------------------------------------------
extern "C" void kernel_launch(void* const* d_in, const int* in_sizes, int n_in,
                              void* d_out, int out_size, void* d_ws, size_t ws_size,
                              hipStream_t stream) {
    const float* x     = (const float*)d_in[0];
    const int*   ei    = (const int*)d_in[1];
    const int*   batch = (const int*)d_in[2];
    const float* Ws    = (const float*)d_in[3];
    const float* bs    = (const float*)d_in[4];
    const float* gammas= (const float*)d_in[5];
    const float* betas = (const float*)d_in[6];
    float* out = (float*)d_out;

    const int* src = ei;
    const int* dst = ei + N_EDGES;

    char* p = (char*)d_ws;
    unsigned short* hbf   = (unsigned short*)p; p += (size_t)N_NODES * D * 2;   // 25.6 MB
    unsigned short* aggx  = (unsigned short*)p; p += (size_t)N_NODES * D * 2;   // 25.6 MB
    unsigned short* Wbt   = (unsigned short*)p; p += (size_t)N_LAYERS * D * D * 2;
    int*   indeg  = (int*)p;   p += (size_t)N_NODES * 4;
    int*   offs   = (int*)p;   p += (size_t)N_NODES * 4;
    int*   cursor = (int*)p;   p += (size_t)N_NODES * 4;
    float* dinv   = (float*)p; p += (size_t)N_NODES * 4;
    int*   bsum   = (int*)p;   p += (size_t)NB_SCAN * 4;
    int*   bbase  = (int*)p;   p += (size_t)NB_SCAN * 4;
    unsigned short* esrc = (unsigned short*)p; p += (size_t)N_EDGES * 2;
    float* sums   = (float*)p; p += (size_t)N_GRAPHS * D * 4;
    int*   counts = (int*)p;   p += (size_t)N_GRAPHS * 4;

    hipMemsetAsync(indeg, 0, (size_t)N_NODES * 4, stream);
    hipMemsetAsync(sums, 0, (size_t)N_GRAPHS * D * 4, stream);

    // graph preprocessing (dinv needed before scaled input conversion)
    k_indeg <<<(N_EDGES + 255) / 256, 256, 0, stream>>>(dst, indeg);
    k_dinv  <<<NB_SCAN, 256, 0, stream>>>(indeg, dinv);
    k_xtobf_s<<<(N_NODES * D / 8 + 255) / 256, 256, 0, stream>>>(x, dinv, hbf);
    k_wtrans<<<(N_LAYERS * D * D + 255) / 256, 256, 0, stream>>>(Ws, Wbt);
    k_bsum  <<<NB_SCAN, 256, 0, stream>>>(indeg, bsum);
    k_bscan <<<1, 256, 0, stream>>>(bsum, bbase);
    k_offsets<<<NB_SCAN, 256, 0, stream>>>(indeg, bbase, offs, cursor);
    k_csr_fill<<<(N_EDGES + 255) / 256, 256, 0, stream>>>(src, dst, cursor, esrc);
    k_counts_bs<<<1, 64, 0, stream>>>(batch, counts);

    // 3 GCN layers: aggregate-first; hs = dinv*h carried between layers
    const int agg_grid  = (N_NODES + 3) / 4;
    const int gemm_grid = (N_NODES + 127) / 128;
    for (int l = 0; l < N_LAYERS; ++l) {
        k_agg<<<agg_grid, 256, 0, stream>>>(hbf, offs, indeg, dinv, esrc, aggx);
        const float* rsc = (l == N_LAYERS - 1) ? nullptr : dinv;
        k_gemm_ln<<<gemm_grid, 256, 0, stream>>>(aggx, Wbt + (size_t)l * D * D,
                                                 bs + (size_t)l * D,
                                                 gammas + (size_t)l * D,
                                                 betas + (size_t)l * D, rsc, hbf);
    }

    // global mean pool (last layer wrote unscaled h)
    k_pool<<<(N_NODES + 127) / 128, 256, 0, stream>>>(hbf, batch, sums);
    k_finalize<<<(N_GRAPHS * 256 + 255) / 256, 256, 0, stream>>>(sums, counts, out);
}

// Round 7
// 416.703 us; speedup vs baseline: 2.0192x; 1.1181x over previous
//
#include <hip/hip_runtime.h>
#include <hip/hip_bf16.h>

#define N_NODES   50000
#define N_EDGES   800000
#define D         256
#define N_LAYERS  3
#define N_GRAPHS  64
#define LN_EPS    1e-5f
#define NB_SCAN   ((N_NODES + 255) / 256)   // 196

typedef __attribute__((ext_vector_type(8))) short bf16x8;
typedef __attribute__((ext_vector_type(4))) float f32x4;

__device__ __forceinline__ unsigned short f2bf(float f) {
    unsigned int u = __float_as_uint(f);
    unsigned int r = (u + 0x7FFFu + ((u >> 16) & 1u)) >> 16;
    return (unsigned short)r;
}
__device__ __forceinline__ float bf2f(unsigned short h) {
    return __uint_as_float(((unsigned int)h) << 16);
}

// ---------------------------------------------------------------------------
// x (fp32) -> bf16 scaled by dinv[row]  (hs0 = dinv * x)
__global__ void k_xtobf_s(const float* __restrict__ x, const float* __restrict__ dinv,
                          unsigned short* __restrict__ xb) {
    int gid = blockIdx.x * blockDim.x + threadIdx.x;      // one per 8 elems
    int base = gid * 8;
    if (base >= N_NODES * D) return;
    float sc = dinv[base >> 8];
    const float4* x4 = (const float4*)(x + base);
    float4 a = x4[0], b = x4[1];
    ushort4 lo, hi;
    lo.x = f2bf(a.x * sc); lo.y = f2bf(a.y * sc); lo.z = f2bf(a.z * sc); lo.w = f2bf(a.w * sc);
    hi.x = f2bf(b.x * sc); hi.y = f2bf(b.y * sc); hi.z = f2bf(b.z * sc); hi.w = f2bf(b.w * sc);
    ((ushort4*)(xb + base))[0] = lo;
    ((ushort4*)(xb + base))[1] = hi;
}

// W [l][k][n] fp32 -> Wbt [l][n][k] bf16 (transposed for MFMA loads)
__global__ void k_wtrans(const float* __restrict__ W, unsigned short* __restrict__ Wbt) {
    int gid = blockIdx.x * blockDim.x + threadIdx.x;
    if (gid >= N_LAYERS * D * D) return;
    int l = gid >> 16;
    int rem = gid & 65535;
    int n = rem >> 8;
    int k = rem & 255;
    Wbt[(size_t)l * D * D + n * D + k] = f2bf(W[(size_t)l * D * D + k * D + n]);
}

// ---------------------------------------------------------------------------
__global__ void k_indeg(const int* __restrict__ dst, int* __restrict__ indeg) {
    int e = blockIdx.x * blockDim.x + threadIdx.x;
    if (e < N_EDGES) atomicAdd(&indeg[dst[e]], 1);
}

__global__ void k_dinv(const int* __restrict__ indeg, float* __restrict__ dinv) {
    int n = blockIdx.x * blockDim.x + threadIdx.x;
    if (n < N_NODES) dinv[n] = rsqrtf((float)(indeg[n] + 1));
}

__global__ __launch_bounds__(256) void k_bsum(const int* __restrict__ indeg, int* __restrict__ bsum) {
    int b = blockIdx.x, t = threadIdx.x;
    int i = b * 256 + t;
    int v = (i < N_NODES) ? indeg[i] : 0;
#pragma unroll
    for (int m = 32; m >= 1; m >>= 1) v += __shfl_xor(v, m);
    __shared__ int s[4];
    if ((t & 63) == 0) s[t >> 6] = v;
    __syncthreads();
    if (t == 0) bsum[b] = s[0] + s[1] + s[2] + s[3];
}

__global__ __launch_bounds__(256) void k_bscan(const int* __restrict__ bsum, int* __restrict__ bbase) {
    __shared__ int s[256];
    int t = threadIdx.x;
    int v = (t < NB_SCAN) ? bsum[t] : 0;
    s[t] = v;
    __syncthreads();
    for (int off = 1; off < 256; off <<= 1) {
        int tv = (t >= off) ? s[t - off] : 0;
        __syncthreads();
        s[t] += tv;
        __syncthreads();
    }
    if (t < NB_SCAN) bbase[t] = s[t] - v;
}

__global__ __launch_bounds__(256) void k_offsets(const int* __restrict__ indeg, const int* __restrict__ bbase,
                                                 int* __restrict__ offsets, int* __restrict__ cursor) {
    __shared__ int s[256];
    int b = blockIdx.x, t = threadIdx.x;
    int i = b * 256 + t;
    int v = (i < N_NODES) ? indeg[i] : 0;
    s[t] = v;
    __syncthreads();
    for (int off = 1; off < 256; off <<= 1) {
        int tv = (t >= off) ? s[t - off] : 0;
        __syncthreads();
        s[t] += tv;
        __syncthreads();
    }
    if (i < N_NODES) {
        int o = bbase[b] + s[t] - v;
        offsets[i] = o;
        cursor[i]  = o;
    }
}

// CSR fill: store only src index as uint16 (N_NODES < 65536)
__global__ void k_csr_fill(const int* __restrict__ src, const int* __restrict__ dst,
                           int* __restrict__ cursor, unsigned short* __restrict__ esrc) {
    int e = blockIdx.x * blockDim.x + threadIdx.x;
    if (e >= N_EDGES) return;
    int s = src[e], d = dst[e];
    int pos = atomicAdd(&cursor[d], 1);
    esrc[pos] = (unsigned short)s;
}

__global__ void k_counts_bs(const int* __restrict__ batch, int* __restrict__ counts) {
    int g = threadIdx.x;
    if (g >= N_GRAPHS) return;
    int lo = 0, hi = N_NODES;
    while (lo < hi) { int mid = (lo + hi) >> 1; if (batch[mid] < g) lo = mid + 1; else hi = mid; }
    int start = lo;
    lo = 0; hi = N_NODES;
    int g1 = g + 1;
    while (lo < hi) { int mid = (lo + hi) >> 1; if (batch[mid] < g1) lo = mid + 1; else hi = mid; }
    counts[g] = lo - start;
}

// ---------------------------------------------------------------------------
// aggregate: agg[n] = dinv[n] * (hs[n] + sum_edges hs[src])
// one wave per node; half-wave (32 lanes x 16 B) covers a full 512 B row;
// 4 edges per half-wave iteration -> 8 rows in flight per wave.
__global__ __launch_bounds__(256) void k_agg(const unsigned short* __restrict__ h,
                                             const int* __restrict__ offsets,
                                             const int* __restrict__ indeg,
                                             const float* __restrict__ dinv,
                                             const unsigned short* __restrict__ esrc,
                                             unsigned short* __restrict__ outA) {
    const int node = blockIdx.x * 4 + (threadIdx.x >> 6);
    const int lane = threadIdx.x & 63;
    if (node >= N_NODES) return;
    const int hw = lane >> 5;       // which edge of the interleaved pair
    const int dl = lane & 31;       // dim-lane: dims dl*8 .. dl*8+7
    const unsigned short* hp = h + dl * 8;

    float acc[8];
    if (hw == 0) {
        bf16x8 v = *(const bf16x8*)(hp + (size_t)node * 256);
#pragma unroll
        for (int j = 0; j < 8; ++j) acc[j] = bf2f((unsigned short)v[j]);
    } else {
#pragma unroll
        for (int j = 0; j < 8; ++j) acc[j] = 0.f;
    }

    const int beg = offsets[node];
    const int end = beg + indeg[node];
    int i = beg + hw;
    for (; i + 6 < end; i += 8) {
        int s0 = esrc[i];
        int s1 = esrc[i + 2];
        int s2 = esrc[i + 4];
        int s3 = esrc[i + 6];
        bf16x8 v0 = *(const bf16x8*)(hp + (size_t)s0 * 256);
        bf16x8 v1 = *(const bf16x8*)(hp + (size_t)s1 * 256);
        bf16x8 v2 = *(const bf16x8*)(hp + (size_t)s2 * 256);
        bf16x8 v3 = *(const bf16x8*)(hp + (size_t)s3 * 256);
#pragma unroll
        for (int j = 0; j < 8; ++j) acc[j] += bf2f((unsigned short)v0[j]);
#pragma unroll
        for (int j = 0; j < 8; ++j) acc[j] += bf2f((unsigned short)v1[j]);
#pragma unroll
        for (int j = 0; j < 8; ++j) acc[j] += bf2f((unsigned short)v2[j]);
#pragma unroll
        for (int j = 0; j < 8; ++j) acc[j] += bf2f((unsigned short)v3[j]);
    }
    for (; i < end; i += 2) {
        int s0 = esrc[i];
        bf16x8 v0 = *(const bf16x8*)(hp + (size_t)s0 * 256);
#pragma unroll
        for (int j = 0; j < 8; ++j) acc[j] += bf2f((unsigned short)v0[j]);
    }

#pragma unroll
    for (int j = 0; j < 8; ++j) acc[j] += __shfl_xor(acc[j], 32);

    if (hw == 0) {
        float sc = dinv[node];
        bf16x8 o;
#pragma unroll
        for (int j = 0; j < 8; ++j) o[j] = (short)f2bf(acc[j] * sc);
        *(bf16x8*)(outA + (size_t)node * 256 + dl * 8) = o;
    }
}

// ---------------------------------------------------------------------------
// fused GEMM + bias + LayerNorm + ReLU (+ optional rowscale)
// block = 512 thr (8 waves) x 64 rows; wave owns a 32-col slice, W-frags in regs.
// A-tile (64x256, 32 KB) staged in LDS, XOR-swizzled 16 B chunks.
// mfma(Wfrag, Afrag): reg-axis = out-col (q*4+r), lane&15 = node-row.
__global__ __launch_bounds__(512) void k_gemm_ln(const unsigned short* __restrict__ A,
                                                 const unsigned short* __restrict__ Wbt,
                                                 const float* __restrict__ bias,
                                                 const float* __restrict__ gamma,
                                                 const float* __restrict__ beta,
                                                 const float* __restrict__ rowscale,
                                                 unsigned short* __restrict__ out) {
    __shared__ short alds[64 * 256];      // 32 KB
    __shared__ float red[2][8][64];       // 4 KB
    const int t = threadIdx.x;
    const int lane = t & 63;
    const int w = t >> 6;                 // wave 0..7
    const int lrow = lane & 15;
    const int q = lane >> 4;              // 0..3
    const int brow = blockIdx.x * 64;
    const int ncb = w * 32;               // this wave's column base

    // persistent W fragments (L2-resident): rows ncb+nt*16+lrow, k = ks*32+q*8
    bf16x8 wf[2][8];
#pragma unroll
    for (int nt = 0; nt < 2; ++nt) {
        const unsigned short* wp = Wbt + (size_t)(ncb + nt * 16 + lrow) * 256 + q * 8;
#pragma unroll
        for (int ks = 0; ks < 8; ++ks)
            wf[nt][ks] = *(const bf16x8*)(wp + ks * 32);
    }

    // stage A tile: 2048 16B-chunks, coalesced read, swizzled ds_write
#pragma unroll
    for (int it = 0; it < 4; ++it) {
        int L = it * 512 + t;
        int r = L >> 5;                   // row in tile 0..63
        int c = L & 31;                   // chunk 0..31
        int row = brow + r; if (row >= N_NODES) row = N_NODES - 1;
        bf16x8 v = *(const bf16x8*)(A + (size_t)row * 256 + c * 8);
        int cs = c ^ (r & 7);
        *(bf16x8*)(alds + r * 256 + cs * 8) = v;
    }
    __syncthreads();

    f32x4 acc[4][2];
#pragma unroll
    for (int mt = 0; mt < 4; ++mt)
#pragma unroll
        for (int nt = 0; nt < 2; ++nt) acc[mt][nt] = (f32x4){0.f, 0.f, 0.f, 0.f};

#pragma unroll
    for (int ks = 0; ks < 8; ++ks) {
        bf16x8 av[4];
#pragma unroll
        for (int mt = 0; mt < 4; ++mt) {
            int cs = (ks * 4 + q) ^ (lrow & 7);
            av[mt] = *(const bf16x8*)(alds + (mt * 16 + lrow) * 256 + cs * 8);
        }
#pragma unroll
        for (int mt = 0; mt < 4; ++mt) {
            acc[mt][0] = __builtin_amdgcn_mfma_f32_16x16x32_bf16(wf[0][ks], av[mt], acc[mt][0], 0, 0, 0);
            acc[mt][1] = __builtin_amdgcn_mfma_f32_16x16x32_bf16(wf[1][ks], av[mt], acc[mt][1], 0, 0, 0);
        }
    }

    // bias + per-wave LN partials (each wave covers 32 of 256 cols)
    const float4* bias4 = (const float4*)bias;
#pragma unroll
    for (int mt = 0; mt < 4; ++mt) {
        float s = 0.f, s2 = 0.f;
#pragma unroll
        for (int nt = 0; nt < 2; ++nt) {
            float4 bv = bias4[w * 8 + nt * 4 + q];
#pragma unroll
            for (int r = 0; r < 4; ++r) {
                float v = acc[mt][nt][r] + ((const float*)&bv)[r];
                acc[mt][nt][r] = v;
                s += v;
                s2 += v * v;
            }
        }
        s  += __shfl_xor(s, 16);  s  += __shfl_xor(s, 32);
        s2 += __shfl_xor(s2, 16); s2 += __shfl_xor(s2, 32);
        if (lane < 16) {
            red[0][w][mt * 16 + lane] = s;
            red[1][w][mt * 16 + lane] = s2;
        }
    }
    __syncthreads();

    const float4* g4 = (const float4*)gamma;
    const float4* be4 = (const float4*)beta;
#pragma unroll
    for (int mt = 0; mt < 4; ++mt) {
        int r = mt * 16 + lrow;
        float s = 0.f, s2 = 0.f;
#pragma unroll
        for (int j = 0; j < 8; ++j) { s += red[0][j][r]; s2 += red[1][j][r]; }
        float mu = s * (1.0f / 256.0f);
        float var = s2 * (1.0f / 256.0f) - mu * mu;
        float rs = rsqrtf(var + LN_EPS);

        int row = brow + r;
        if (row < N_NODES) {
            float sc = (rowscale != nullptr) ? rowscale[row] : 1.0f;
#pragma unroll
            for (int nt = 0; nt < 2; ++nt) {
                float4 gv = g4[w * 8 + nt * 4 + q];
                float4 bev = be4[w * 8 + nt * 4 + q];
                ushort4 o;
                float v0 = fmaxf((acc[mt][nt][0] - mu) * rs * gv.x + bev.x, 0.f) * sc;
                float v1 = fmaxf((acc[mt][nt][1] - mu) * rs * gv.y + bev.y, 0.f) * sc;
                float v2 = fmaxf((acc[mt][nt][2] - mu) * rs * gv.z + bev.z, 0.f) * sc;
                float v3 = fmaxf((acc[mt][nt][3] - mu) * rs * gv.w + bev.w, 0.f) * sc;
                o.x = f2bf(v0); o.y = f2bf(v1); o.z = f2bf(v2); o.w = f2bf(v3);
                *(ushort4*)(out + (size_t)row * 256 + ncb + nt * 16 + q * 4) = o;
            }
        }
    }
}

// ---------------------------------------------------------------------------
__global__ __launch_bounds__(256) void k_pool(const unsigned short* __restrict__ h,
                                              const int* __restrict__ batch,
                                              float* __restrict__ sums) {
    __shared__ int sb[128];
    int t = threadIdx.x;
    int n0 = blockIdx.x * 128;
    int cnt = N_NODES - n0; if (cnt > 128) cnt = 128;
    if (cnt <= 0) return;
    if (t < cnt) sb[t] = batch[n0 + t];
    __syncthreads();

    float acc = 0.f;
    int g = sb[0];
    for (int i = 0; i < cnt; ++i) {
        int bg = sb[i];
        if (bg != g) {
            atomicAdd(&sums[g * 256 + t], acc);
            acc = 0.f;
            g = bg;
        }
        acc += bf2f(h[(size_t)(n0 + i) * 256 + t]);
    }
    atomicAdd(&sums[g * 256 + t], acc);
}

__global__ void k_finalize(const float* __restrict__ sums, const int* __restrict__ counts,
                           float* __restrict__ out) {
    int idx = blockIdx.x * blockDim.x + threadIdx.x;
    if (idx < N_GRAPHS * 256) {
        float c = (float)counts[idx >> 8];
        out[idx] = sums[idx] / fmaxf(c, 1.f);
    }
}

// ---------------------------------------------------------------------------
extern "C" void kernel_launch(void* const* d_in, const int* in_sizes, int n_in,
                              void* d_out, int out_size, void* d_ws, size_t ws_size,
                              hipStream_t stream) {
    const float* x     = (const float*)d_in[0];
    const int*   ei    = (const int*)d_in[1];
    const int*   batch = (const int*)d_in[2];
    const float* Ws    = (const float*)d_in[3];
    const float* bs    = (const float*)d_in[4];
    const float* gammas= (const float*)d_in[5];
    const float* betas = (const float*)d_in[6];
    float* out = (float*)d_out;

    const int* src = ei;
    const int* dst = ei + N_EDGES;

    char* p = (char*)d_ws;
    unsigned short* hbf   = (unsigned short*)p; p += (size_t)N_NODES * D * 2;   // 25.6 MB
    unsigned short* aggx  = (unsigned short*)p; p += (size_t)N_NODES * D * 2;   // 25.6 MB
    unsigned short* Wbt   = (unsigned short*)p; p += (size_t)N_LAYERS * D * D * 2;
    int*   indeg  = (int*)p;   p += (size_t)N_NODES * 4;
    int*   offs   = (int*)p;   p += (size_t)N_NODES * 4;
    int*   cursor = (int*)p;   p += (size_t)N_NODES * 4;
    float* dinv   = (float*)p; p += (size_t)N_NODES * 4;
    int*   bsum   = (int*)p;   p += (size_t)NB_SCAN * 4;
    int*   bbase  = (int*)p;   p += (size_t)NB_SCAN * 4;
    unsigned short* esrc = (unsigned short*)p; p += (size_t)N_EDGES * 2;
    float* sums   = (float*)p; p += (size_t)N_GRAPHS * D * 4;
    int*   counts = (int*)p;   p += (size_t)N_GRAPHS * 4;

    hipMemsetAsync(indeg, 0, (size_t)N_NODES * 4, stream);
    hipMemsetAsync(sums, 0, (size_t)N_GRAPHS * D * 4, stream);

    // graph preprocessing
    k_indeg <<<(N_EDGES + 255) / 256, 256, 0, stream>>>(dst, indeg);
    k_dinv  <<<NB_SCAN, 256, 0, stream>>>(indeg, dinv);
    k_xtobf_s<<<(N_NODES * D / 8 + 255) / 256, 256, 0, stream>>>(x, dinv, hbf);
    k_wtrans<<<(N_LAYERS * D * D + 255) / 256, 256, 0, stream>>>(Ws, Wbt);
    k_bsum  <<<NB_SCAN, 256, 0, stream>>>(indeg, bsum);
    k_bscan <<<1, 256, 0, stream>>>(bsum, bbase);
    k_offsets<<<NB_SCAN, 256, 0, stream>>>(indeg, bbase, offs, cursor);
    k_csr_fill<<<(N_EDGES + 255) / 256, 256, 0, stream>>>(src, dst, cursor, esrc);
    k_counts_bs<<<1, 64, 0, stream>>>(batch, counts);

    // 3 GCN layers: aggregate-first; hs = dinv*h carried between layers
    const int agg_grid  = (N_NODES + 3) / 4;
    const int gemm_grid = (N_NODES + 63) / 64;
    for (int l = 0; l < N_LAYERS; ++l) {
        k_agg<<<agg_grid, 256, 0, stream>>>(hbf, offs, indeg, dinv, esrc, aggx);
        const float* rsc = (l == N_LAYERS - 1) ? nullptr : dinv;
        k_gemm_ln<<<gemm_grid, 512, 0, stream>>>(aggx, Wbt + (size_t)l * D * D,
                                                 bs + (size_t)l * D,
                                                 gammas + (size_t)l * D,
                                                 betas + (size_t)l * D, rsc, hbf);
    }

    // global mean pool (last layer wrote unscaled h)
    k_pool<<<(N_NODES + 127) / 128, 256, 0, stream>>>(hbf, batch, sums);
    k_finalize<<<(N_GRAPHS * 256 + 255) / 256, 256, 0, stream>>>(sums, counts, out);
}